// Round 5
// baseline (103.700 us; speedup 1.0000x reference)
//
#include <hip/hip_runtime.h>

#define IS 256
#define FCOUNT 4096
#define NEARP 0.1f
#define FARP 100.0f
#define TINYF 1e-12f
#define CAP 192          // per-8x8-bin capacity (mean ~25; Poisson tail << CAP; R0-proven)
#define GCAP 128         // per-image sliver-list capacity (R0-proven)
#define DET_GLOBAL 1e-5f // |det| below this -> per-image list (escape unbounded)
#define ZEPS 2e-4f       // early-z slack: zp >= min(z)-5e-5 proven; 4x margin

// Value barrier: pins a value in a VGPR; no transform across it.
__device__ __forceinline__ float frn(float r) { asm("" : "+v"(r)); return r; }
__device__ __forceinline__ float mulrn(float a, float b) { return frn(a * b); }
__device__ __forceinline__ float addrn(float a, float b) { return frn(a + b); }
__device__ __forceinline__ float subrn(float a, float b) { return frn(a - b); }
__device__ __forceinline__ float divrn(float a, float b) { return frn(a / b); }
__device__ __forceinline__ float fmarn(float a, float b, float c) {
    return frn(__builtin_fmaf(a, b, c));
}

// ---------------------------------------------------------------------------
// R5 structure: back to two dispatches (R2 vs R0 comparison proved extra
// dispatches cost ~1-2 us, not 10), fixing the two invariants that kept
// R2-R4 at ~43 us: (a) phase-A replication — every one of 1024 blocks
// re-scanned all 4096 faces; binning now happens ONCE (16K face-threads);
// (b) no-backfill tail — grid was exactly residency capacity, so runtime =
// slowest 256-thread block. Raster blocks are now 1 wave = one 8x8 bin
// (4096 blocks, 16/CU): fine-grained units retire independently.
// Cross-dispatch visibility of cA/cB/cC/lists: same-stream kernel ordering
// (R0-proven on this harness).
// ---------------------------------------------------------------------------

// ---------- pass 1: per-face constants + bin into 8x8-px tiles (32x32) ------
// R0-verified body + R3's coalesced LDS staging (64 faces/wave via float4).
// Escape bound: fp-inside region extends <= ~6e-8/|det| beyond the hull;
// dilate 2e-3 + 3e-7/|det| (5x safety, <= 0.032). |det| < 1e-5 -> one atomic
// into the per-image global list.
__global__ __launch_bounds__(64) void bin_kernel(
    const float* __restrict__ faces,
    float4* __restrict__ cA, float4* __restrict__ cB, float4* __restrict__ cC,
    int* __restrict__ counts, int* __restrict__ lists,
    int* __restrict__ gcount, int* __restrict__ glist, int B, int F)
{
    const int lane = threadIdx.x;           // block = 1 wave
    const int base = blockIdx.x * 64;       // face-group base in [0, B*F)
    const int gid  = base + lane;
    if (gid >= B * F) return;               // B*F % 64 == 0: never splits a wave
    const int b = gid >> 12, f = gid & (FCOUNT - 1);   // F == 4096

    __shared__ float4 stage4[144];          // 576 floats = 64 faces
    float* stage = (float*)stage4;
    const float* src = faces + (size_t)base * 9;   // 16B-aligned (base%64==0)
    const float4* s4 = (const float4*)src;
    stage4[lane]      = s4[lane];
    stage4[64 + lane] = s4[64 + lane];
    stage[512 + lane] = src[512 + lane];
    __builtin_amdgcn_wave_barrier();        // order LDS write -> read (free)

    const float* fp = stage + lane * 9;     // stride-9 words: 2-way = free
    const float x0 = fp[0], y0 = fp[1], z0 = fp[2];
    const float x1 = fp[3], y1 = fp[4], z1 = fp[5];
    const float x2 = fp[6], y2 = fp[7], z2 = fp[8];

    // Verified contracted numerics: C = fma(xa, yb, -(xb*ya)).
    const float A0 = subrn(x2, x1), B0 = subrn(y1, y2);
    const float C0 = fmarn(x1, y2, -mulrn(x2, y1));
    const float A1 = subrn(x0, x2), B1 = subrn(y2, y0);
    const float C1 = fmarn(x2, y0, -mulrn(x0, y2));
    const float A2 = subrn(x1, x0), B2 = subrn(y0, y1);
    const float C2 = fmarn(x0, y1, -mulrn(x1, y0));
    cA[gid] = make_float4(A0, B0, C0, A1);
    cB[gid] = make_float4(B1, C1, A2, B2);
    cC[gid] = make_float4(C2, z0, z1, z2);

    const float det = (x1 - x0) * (y2 - y0) - (x2 - x0) * (y1 - y0);
    const float ad = fabsf(det);
    if (ad < DET_GLOBAL) {
        const int pos = atomicAdd(&gcount[b], 1);
        if (pos < GCAP) glist[b * GCAP + pos] = f;
        return;
    }
    const float d = 2e-3f + 3e-7f / ad;   // <= 0.032
    const float lox = fminf(x0, fminf(x1, x2)) - d;
    const float hix = fmaxf(x0, fmaxf(x1, x2)) + d;
    const float loy = fminf(y0, fminf(y1, y2)) - d;
    const float hiy = fmaxf(y0, fmaxf(y1, y2)) + d;
    // 8-px tile t: xp in [(16t+1-256)/256, (16t+15-256)/256].
    // Overlap: t >= (256*lo+241)/16 and t <= (256*hi+255)/16. Dilation d
    // (>=2e-3 = 0.5 NDC px) dwarfs the ~1e-7 fp slack of these bounds.
    int tx0 = (int)ceilf ((256.f * lox + 241.f) * (1.f / 16.f));
    int tx1 = (int)floorf((256.f * hix + 255.f) * (1.f / 16.f));
    int ty0 = (int)ceilf ((256.f * loy + 241.f) * (1.f / 16.f));
    int ty1 = (int)floorf((256.f * hiy + 255.f) * (1.f / 16.f));
    tx0 = max(tx0, 0); tx1 = min(tx1, 31);
    ty0 = max(ty0, 0); ty1 = min(ty1, 31);
    for (int ty = ty0; ty <= ty1; ++ty)
        for (int tx = tx0; tx <= tx1; ++tx) {
            const int t = (b * 32 + ty) * 32 + tx;
            const int pos = atomicAdd(&counts[t], 1);
            if (pos < CAP) lists[(size_t)t * CAP + pos] = f;
        }
}

// ---------- pass 2: rasterize — ONE WAVE per 8x8 bin ------------------------
// 4096 independent 64-thread blocks (16/CU): dense bins retire alone, no
// 256-thread-block straggler coupling, scheduler backfills. Per-face loads
// are wave-uniform-address (L1 broadcast) and software-pipelined one ahead.
// Eval chain + early-z + win-state saving: R2/R3-verified, op-for-op.
__global__ __launch_bounds__(64) void raster_kernel(
    const float* __restrict__ textures,
    const float4* __restrict__ cA, const float4* __restrict__ cB,
    const float4* __restrict__ cC,
    const int* __restrict__ counts, const int* __restrict__ lists,
    const int* __restrict__ gcount, const int* __restrict__ glist,
    float* __restrict__ out, int B, int F)
{
    const int lane = threadIdx.x;
    const int blk  = blockIdx.x;            // b*1024 + ty*32 + tx
    const int b    = blk >> 10;
    const int tx   = blk & 31;
    const int ty   = (blk >> 5) & 31;
    const int bin  = (b * 32 + ty) * 32 + tx;  // same layout as bin_kernel
    const int px   = tx * 8 + (lane & 7);
    const int py   = ty * 8 + (lane >> 3);
    const float xp = (float)(2 * px + 1 - IS) * (1.0f / IS);  // exact (/2^8)
    const float yp = (float)(2 * py + 1 - IS) * (1.0f / IS);  // exact

    const int cnt   = min(counts[bin], CAP);
    const int gcnt  = min(gcount[b], GCAP);
    const int total = cnt + gcnt;
    const int* mylist = lists + (size_t)bin * CAP;
    const int* gl     = glist + b * GCAP;
    const int fb = b * F;

    float bestz = FARP;
    int   besti = -1;
    float bn0 = 0.f, bn1 = 0.f, bn2 = 0.f;     // winner's normalized weights
    float bz0 = 1.f, bz1 = 1.f, bz2 = 1.f;     // winner's vertex depths

    // Software pipeline: constants for face j+1 load during face j's eval.
    int    pf = 0;
    float4 pa, pb, pc;
    if (total > 0) {
        pf = (0 < cnt) ? mylist[0] : gl[0];
        pa = cA[fb + pf]; pb = cB[fb + pf]; pc = cC[fb + pf];
    }
    for (int j = 0; j < total; ++j) {
        const float4 fa  = pa;
        const float4 fb4 = pb;
        const float4 fc  = pc;
        const int    fi  = pf;
        const int jn = j + 1;
        if (jn < total) {
            pf = (jn < cnt) ? mylist[jn] : gl[jn - cnt];
            pa = cA[fb + pf]; pb = cB[fb + pf]; pc = cC[fb + pf];
        }
        // Contracted: w = fma(yp, A, xp*B) + C  (verified chain)
        const float w0 = addrn(fmarn(yp, fa.x, mulrn(xp, fa.y)), fa.z);
        const float w1 = addrn(fmarn(yp, fa.w, mulrn(xp, fb4.x)), fb4.y);
        const float w2 = addrn(fmarn(yp, fb4.z, mulrn(xp, fb4.w)), fc.x);
        const float det = addrn(addrn(w0, w1), w2);
        bool ins;
        if (det > TINYF)       ins = (w0 > 0.f) && (w1 > 0.f) && (w2 > 0.f);
        else if (det < -TINYF) ins = (w0 < 0.f) && (w1 < 0.f) && (w2 < 0.f);
        else                   ins = false;
        // Early-z: zp >= min(z) - ~5e-5 (clipped weights sum ~1), so a face
        // with min(z) > bestz+ZEPS can neither win nor tie.
        const float minz = fminf(fminf(fc.y, fc.z), fc.w);
        if (ins && minz <= bestz + ZEPS) {
            float n0 = divrn(w0, det), n1 = divrn(w1, det), n2 = divrn(w2, det);
            n0 = frn(fminf(fmaxf(n0, 0.f), 1.f));
            n1 = frn(fminf(fmaxf(n1, 0.f), 1.f));
            n2 = frn(fminf(fmaxf(n2, 0.f), 1.f));
            float s = addrn(addrn(n0, n1), n2);
            s = (s > TINYF) ? s : 1.0f;
            n0 = divrn(n0, s); n1 = divrn(n1, s); n2 = divrn(n2, s);
            float iz = addrn(addrn(divrn(n0, fc.y), divrn(n1, fc.z)),
                             divrn(n2, fc.w));
            iz = (fabsf(iz) > TINYF) ? iz : 1.0f;
            const float zp = divrn(1.0f, iz);
            if (zp > NEARP && zp < FARP) {
                if (zp < bestz || (zp == bestz && fi < besti)) {
                    bestz = zp;
                    besti = fi;
                    bn0 = n0; bn1 = n1; bn2 = n2;
                    bz0 = fc.y; bz1 = fc.z; bz2 = fc.w;
                }
            }
        }
    }

    // ---- shade the winner from saved state (R3-verified: no reload, the
    // saved n0,n1,n2,zp are bit-identical to the reference recompute) -------
    float r = 0.f, g = 0.f, bch = 0.f, alpha = 0.f, depth = FARP;
    if (besti >= 0) {
        const float zp = bestz;
        depth = zp;
        const float t0 = fminf(fmaxf(divrn(mulrn(mulrn(bn0, 3.0f), zp), bz0), 0.f), 2.999f);
        const float t1 = fminf(fmaxf(divrn(mulrn(mulrn(bn1, 3.0f), zp), bz1), 0.f), 2.999f);
        const float t2 = fminf(fmaxf(divrn(mulrn(mulrn(bn2, 3.0f), zp), bz2), 0.f), 2.999f);
        const float l0 = floorf(t0), l1 = floorf(t1), l2 = floorf(t2);
        const float fr0 = subrn(t0, l0), fr1 = subrn(t1, l1), fr2 = subrn(t2, l2);
        const int i0 = (int)l0, i1 = (int)l1, i2 = (int)l2;

        const float* txp = textures + (size_t)(b * F + besti) * 64 * 3;
        for (int d0 = 0; d0 < 2; ++d0)
            for (int d1 = 0; d1 < 2; ++d1)
                for (int d2 = 0; d2 < 2; ++d2) {
                    const float wg = mulrn(mulrn(d0 ? fr0 : subrn(1.0f, fr0),
                                                 d1 ? fr1 : subrn(1.0f, fr1)),
                                           d2 ? fr2 : subrn(1.0f, fr2));
                    const float* tp = txp + ((i0 + d0) * 16 + (i1 + d1) * 4 + (i2 + d2)) * 3;
                    r   = addrn(r,   mulrn(wg, tp[0]));
                    g   = addrn(g,   mulrn(wg, tp[1]));
                    bch = addrn(bch, mulrn(wg, tp[2]));
                }
        alpha = 1.0f;
    }

    float* op = out + (((size_t)b * IS + py) * IS + px) * 5;
    op[0] = r;
    op[1] = g;
    op[2] = bch;
    op[3] = alpha;
    op[4] = depth;
}

extern "C" void kernel_launch(void* const* d_in, const int* in_sizes, int n_in,
                              void* d_out, int out_size, void* d_ws, size_t ws_size,
                              hipStream_t stream) {
    const float* faces    = (const float*)d_in[0];
    const float* textures = (const float*)d_in[1];
    float* out = (float*)d_out;
    const int F = FCOUNT;
    const int B = in_sizes[0] / (F * 9);
    const int nbins = B * 1024;          // 32x32 bins per image

    int* counts = (int*)d_ws;                       // nbins ints
    int* gcount = counts + nbins;                   // B ints
    int* glist  = gcount + B;                       // B*GCAP ints
    int* lists  = glist + B * GCAP;                 // nbins*CAP ints
    float4* cA  = (float4*)(lists + (size_t)nbins * CAP);   // B*F float4
    float4* cB  = cA + (size_t)B * F;
    float4* cC  = cB + (size_t)B * F;

    hipMemsetAsync(counts, 0, (size_t)(nbins + B) * sizeof(int), stream);
    bin_kernel<<<dim3((B * F + 63) / 64), dim3(64), 0, stream>>>(
        faces, cA, cB, cC, counts, lists, gcount, glist, B, F);
    raster_kernel<<<dim3(B * 1024), dim3(64), 0, stream>>>(
        textures, cA, cB, cC, counts, lists, gcount, glist, out, B, F);
}

// Round 6
// 101.527 us; speedup vs baseline: 1.0214x; 1.0214x over previous
//
#include <hip/hip_runtime.h>

#define IS 256
#define FCOUNT 4096
#define NEARP 0.1f
#define FARP 100.0f
#define TINYF 1e-12f
#define CAP 192          // per-8x8-bin capacity (mean ~25-48; Poisson tail << CAP)
#define GCAP 128         // per-image sliver-list capacity (R0-proven)
#define DET_GLOBAL 1e-5f // |det| below this -> per-image list (escape unbounded)
#define ZEPS 2e-4f       // early-z slack: zp >= min(z)-5e-5 proven; 4x margin

// Value barrier: pins a value in a VGPR; no transform across it.
__device__ __forceinline__ float frn(float r) { asm("" : "+v"(r)); return r; }
__device__ __forceinline__ float mulrn(float a, float b) { return frn(a * b); }
__device__ __forceinline__ float addrn(float a, float b) { return frn(a + b); }
__device__ __forceinline__ float subrn(float a, float b) { return frn(a - b); }
__device__ __forceinline__ float divrn(float a, float b) { return frn(a / b); }
__device__ __forceinline__ float fmarn(float a, float b, float c) {
    return frn(__builtin_fmaf(a, b, c));
}

// ---------------------------------------------------------------------------
// R6: face-striped raster + LDS merge + oversubscription.
// R2-R5 post-mortem: raster pinned at ~40-43 us across four structures while
// VALUBusy ~46% / Occupancy ~26% and all instruction-count attacks were null
// -> the invariant was "one wave serially owns one bin, grid == residency".
// Runtime = straggler waves (dense bins x ~150-200 cyc/face load-to-branch
// chains), not mean VALU work. Fix: 4 waves per bin, bin list STRIPED across
// waves (wave s takes entries s, s+4, ...), all waves cover the same 64 px;
// exact per-stripe partial argmin (verified chain; early-z bound is absolute
// so per-stripe culling stays exact); LDS merge by (z, smaller idx) — the
// reference tie-break, order-independent (relied on since R0: bins are
// atomic-ordered). 4096 blocks x 256 thr with launch_bounds(256,8):
// straggler work /4, up to 8 waves/SIMD, 4 rounds of backfill.
// ---------------------------------------------------------------------------

// ---------- pass 1: per-face constants + bin into 8x8-px tiles (32x32) ------
// R0-verified body + R3's coalesced LDS staging (64 faces/wave via float4).
// Escape bound: fp-inside region extends <= ~6e-8/|det| beyond the hull;
// dilate 2e-3 + 3e-7/|det| (5x safety, <= 0.032). |det| < 1e-5 -> one atomic
// into the per-image global list.
__global__ __launch_bounds__(64) void bin_kernel(
    const float* __restrict__ faces,
    float4* __restrict__ cA, float4* __restrict__ cB, float4* __restrict__ cC,
    int* __restrict__ counts, int* __restrict__ lists,
    int* __restrict__ gcount, int* __restrict__ glist, int B, int F)
{
    const int lane = threadIdx.x;           // block = 1 wave
    const int base = blockIdx.x * 64;       // face-group base in [0, B*F)
    const int gid  = base + lane;
    if (gid >= B * F) return;               // B*F % 64 == 0: never splits a wave
    const int b = gid >> 12, f = gid & (FCOUNT - 1);   // F == 4096

    __shared__ float4 stage4[144];          // 576 floats = 64 faces
    float* stage = (float*)stage4;
    const float* src = faces + (size_t)base * 9;   // 16B-aligned (base%64==0)
    const float4* s4 = (const float4*)src;
    stage4[lane]      = s4[lane];
    stage4[64 + lane] = s4[64 + lane];
    stage[512 + lane] = src[512 + lane];
    __builtin_amdgcn_wave_barrier();        // order LDS write -> read (free)

    const float* fp = stage + lane * 9;     // stride-9 words: 2-way = free
    const float x0 = fp[0], y0 = fp[1], z0 = fp[2];
    const float x1 = fp[3], y1 = fp[4], z1 = fp[5];
    const float x2 = fp[6], y2 = fp[7], z2 = fp[8];

    // Verified contracted numerics: C = fma(xa, yb, -(xb*ya)).
    const float A0 = subrn(x2, x1), B0 = subrn(y1, y2);
    const float C0 = fmarn(x1, y2, -mulrn(x2, y1));
    const float A1 = subrn(x0, x2), B1 = subrn(y2, y0);
    const float C1 = fmarn(x2, y0, -mulrn(x0, y2));
    const float A2 = subrn(x1, x0), B2 = subrn(y0, y1);
    const float C2 = fmarn(x0, y1, -mulrn(x1, y0));
    cA[gid] = make_float4(A0, B0, C0, A1);
    cB[gid] = make_float4(B1, C1, A2, B2);
    cC[gid] = make_float4(C2, z0, z1, z2);

    const float det = (x1 - x0) * (y2 - y0) - (x2 - x0) * (y1 - y0);
    const float ad = fabsf(det);
    if (ad < DET_GLOBAL) {
        const int pos = atomicAdd(&gcount[b], 1);
        if (pos < GCAP) glist[b * GCAP + pos] = f;
        return;
    }
    const float d = 2e-3f + 3e-7f / ad;   // <= 0.032
    const float lox = fminf(x0, fminf(x1, x2)) - d;
    const float hix = fmaxf(x0, fmaxf(x1, x2)) + d;
    const float loy = fminf(y0, fminf(y1, y2)) - d;
    const float hiy = fmaxf(y0, fmaxf(y1, y2)) + d;
    // 8-px tile t: xp in [(16t+1-256)/256, (16t+15-256)/256].
    // Overlap: t >= (256*lo+241)/16 and t <= (256*hi+255)/16. Dilation d
    // (>=2e-3 = 0.5 NDC px) dwarfs the ~1e-7 fp slack of these bounds.
    int tx0 = (int)ceilf ((256.f * lox + 241.f) * (1.f / 16.f));
    int tx1 = (int)floorf((256.f * hix + 255.f) * (1.f / 16.f));
    int ty0 = (int)ceilf ((256.f * loy + 241.f) * (1.f / 16.f));
    int ty1 = (int)floorf((256.f * hiy + 255.f) * (1.f / 16.f));
    tx0 = max(tx0, 0); tx1 = min(tx1, 31);
    ty0 = max(ty0, 0); ty1 = min(ty1, 31);
    for (int ty = ty0; ty <= ty1; ++ty)
        for (int tx = tx0; tx <= tx1; ++tx) {
            const int t = (b * 32 + ty) * 32 + tx;
            const int pos = atomicAdd(&counts[t], 1);
            if (pos < CAP) lists[(size_t)t * CAP + pos] = f;
        }
}

// ---------- pass 2: rasterize — 4 waves per 8x8 bin, face-striped -----------
__global__ __launch_bounds__(256, 8) void raster_kernel(
    const float* __restrict__ textures,
    const float4* __restrict__ cA, const float4* __restrict__ cB,
    const float4* __restrict__ cC,
    const int* __restrict__ counts, const int* __restrict__ lists,
    const int* __restrict__ gcount, const int* __restrict__ glist,
    float* __restrict__ out, int B, int F)
{
    const int tid  = threadIdx.x;
    const int lane = tid & 63;
    const int w    = tid >> 6;
    const int blk  = blockIdx.x;            // b*1024 + ty*32 + tx
    const int b    = blk >> 10;
    const int tx   = blk & 31;
    const int ty   = (blk >> 5) & 31;
    const int bin  = (b * 32 + ty) * 32 + tx;  // same layout as bin_kernel
    const int px   = tx * 8 + (lane & 7);
    const int py   = ty * 8 + (lane >> 3);
    const float xp = (float)(2 * px + 1 - IS) * (1.0f / IS);  // exact (/2^8)
    const float yp = (float)(2 * py + 1 - IS) * (1.0f / IS);  // exact

    // Per-wave partial results (stride-3/1 word layouts: no systematic bank hit)
    __shared__ float s_pz[4][64];
    __shared__ int   s_pi[4][64];
    __shared__ float s_pn[4][64][3];
    __shared__ float s_pvz[4][64][3];

    const int cnt   = min(counts[bin], CAP);
    const int gcnt  = min(gcount[b], GCAP);
    const int total = cnt + gcnt;
    const int* mylist = lists + (size_t)bin * CAP;
    const int* gl     = glist + b * GCAP;
    const int fb = b * F;

    float bestz = FARP;
    int   besti = -1;
    float bn0 = 0.f, bn1 = 0.f, bn2 = 0.f;     // winner's normalized weights
    float bz0 = 1.f, bz1 = 1.f, bz2 = 1.f;     // winner's vertex depths

    // Stripe: wave w evaluates list entries w, w+4, w+8, ... (exact partition).
    // Software pipeline: constants for the next stripe entry load during eval.
    int    pf = 0;
    float4 pa, pb, pc;
    if (w < total) {
        pf = (w < cnt) ? mylist[w] : gl[w - cnt];
        pa = cA[fb + pf]; pb = cB[fb + pf]; pc = cC[fb + pf];
    }
    for (int j = w; j < total; j += 4) {
        const float4 fa  = pa;
        const float4 fb4 = pb;
        const float4 fc  = pc;
        const int    fi  = pf;
        const int jn = j + 4;
        if (jn < total) {
            pf = (jn < cnt) ? mylist[jn] : gl[jn - cnt];
            pa = cA[fb + pf]; pb = cB[fb + pf]; pc = cC[fb + pf];
        }
        // Contracted: w = fma(yp, A, xp*B) + C  (verified chain)
        const float w0 = addrn(fmarn(yp, fa.x, mulrn(xp, fa.y)), fa.z);
        const float w1 = addrn(fmarn(yp, fa.w, mulrn(xp, fb4.x)), fb4.y);
        const float w2 = addrn(fmarn(yp, fb4.z, mulrn(xp, fb4.w)), fc.x);
        const float det = addrn(addrn(w0, w1), w2);
        bool ins;
        if (det > TINYF)       ins = (w0 > 0.f) && (w1 > 0.f) && (w2 > 0.f);
        else if (det < -TINYF) ins = (w0 < 0.f) && (w1 < 0.f) && (w2 < 0.f);
        else                   ins = false;
        // Early-z: zp >= min(z) - ~5e-5 (absolute bound), so a face with
        // min(z) > bestz+ZEPS can neither win nor tie — exact per stripe.
        const float minz = fminf(fminf(fc.y, fc.z), fc.w);
        if (ins && minz <= bestz + ZEPS) {
            float n0 = divrn(w0, det), n1 = divrn(w1, det), n2 = divrn(w2, det);
            n0 = frn(fminf(fmaxf(n0, 0.f), 1.f));
            n1 = frn(fminf(fmaxf(n1, 0.f), 1.f));
            n2 = frn(fminf(fmaxf(n2, 0.f), 1.f));
            float s = addrn(addrn(n0, n1), n2);
            s = (s > TINYF) ? s : 1.0f;
            n0 = divrn(n0, s); n1 = divrn(n1, s); n2 = divrn(n2, s);
            float iz = addrn(addrn(divrn(n0, fc.y), divrn(n1, fc.z)),
                             divrn(n2, fc.w));
            iz = (fabsf(iz) > TINYF) ? iz : 1.0f;
            const float zp = divrn(1.0f, iz);
            if (zp > NEARP && zp < FARP) {
                if (zp < bestz || (zp == bestz && fi < besti)) {
                    bestz = zp;
                    besti = fi;
                    bn0 = n0; bn1 = n1; bn2 = n2;
                    bz0 = fc.y; bz1 = fc.z; bz2 = fc.w;
                }
            }
        }
    }

    // Publish partials.
    s_pz[w][lane] = bestz;
    s_pi[w][lane] = besti;
    s_pn[w][lane][0]  = bn0; s_pn[w][lane][1]  = bn1; s_pn[w][lane][2]  = bn2;
    s_pvz[w][lane][0] = bz0; s_pvz[w][lane][1] = bz1; s_pvz[w][lane][2] = bz2;
    __syncthreads();

    // Wave 0: merge 4 partials per pixel — lexicographic (z, smaller idx) =
    // the reference argmin tie-break (empty partial: z=FARP, idx=-1; a real
    // winner has z<FARP strictly, so it always beats empty; FARP ties have
    // both idx=-1). Then shade from the winning partial's saved state
    // (R3-verified: no face reload, no divide chain).
    if (w == 0) {
        float z = s_pz[0][lane];
        int   i = s_pi[0][lane];
        int  ws = 0;
        #pragma unroll
        for (int s = 1; s < 4; ++s) {
            const float zs = s_pz[s][lane];
            const int   is = s_pi[s][lane];
            if (zs < z || (zs == z && is < i)) { z = zs; i = is; ws = s; }
        }

        float r = 0.f, g = 0.f, bch = 0.f, alpha = 0.f, depth = FARP;
        if (i >= 0) {
            const float n0 = s_pn[ws][lane][0];
            const float n1 = s_pn[ws][lane][1];
            const float n2 = s_pn[ws][lane][2];
            const float z0 = s_pvz[ws][lane][0];
            const float z1 = s_pvz[ws][lane][1];
            const float z2 = s_pvz[ws][lane][2];
            const float zp = z;
            depth = zp;
            const float t0 = fminf(fmaxf(divrn(mulrn(mulrn(n0, 3.0f), zp), z0), 0.f), 2.999f);
            const float t1 = fminf(fmaxf(divrn(mulrn(mulrn(n1, 3.0f), zp), z1), 0.f), 2.999f);
            const float t2 = fminf(fmaxf(divrn(mulrn(mulrn(n2, 3.0f), zp), z2), 0.f), 2.999f);
            const float l0 = floorf(t0), l1 = floorf(t1), l2 = floorf(t2);
            const float fr0 = subrn(t0, l0), fr1 = subrn(t1, l1), fr2 = subrn(t2, l2);
            const int i0 = (int)l0, i1 = (int)l1, i2 = (int)l2;

            const float* txp = textures + (size_t)(b * F + i) * 64 * 3;
            for (int d0 = 0; d0 < 2; ++d0)
                for (int d1 = 0; d1 < 2; ++d1)
                    for (int d2 = 0; d2 < 2; ++d2) {
                        const float wg = mulrn(mulrn(d0 ? fr0 : subrn(1.0f, fr0),
                                                     d1 ? fr1 : subrn(1.0f, fr1)),
                                               d2 ? fr2 : subrn(1.0f, fr2));
                        const float* tp = txp + ((i0 + d0) * 16 + (i1 + d1) * 4 + (i2 + d2)) * 3;
                        r   = addrn(r,   mulrn(wg, tp[0]));
                        g   = addrn(g,   mulrn(wg, tp[1]));
                        bch = addrn(bch, mulrn(wg, tp[2]));
                    }
            alpha = 1.0f;
        }

        float* op = out + (((size_t)b * IS + py) * IS + px) * 5;
        op[0] = r;
        op[1] = g;
        op[2] = bch;
        op[3] = alpha;
        op[4] = depth;
    }
}

extern "C" void kernel_launch(void* const* d_in, const int* in_sizes, int n_in,
                              void* d_out, int out_size, void* d_ws, size_t ws_size,
                              hipStream_t stream) {
    const float* faces    = (const float*)d_in[0];
    const float* textures = (const float*)d_in[1];
    float* out = (float*)d_out;
    const int F = FCOUNT;
    const int B = in_sizes[0] / (F * 9);
    const int nbins = B * 1024;          // 32x32 bins per image

    int* counts = (int*)d_ws;                       // nbins ints
    int* gcount = counts + nbins;                   // B ints
    int* glist  = gcount + B;                       // B*GCAP ints
    int* lists  = glist + B * GCAP;                 // nbins*CAP ints
    float4* cA  = (float4*)(lists + (size_t)nbins * CAP);   // B*F float4
    float4* cB  = cA + (size_t)B * F;
    float4* cC  = cB + (size_t)B * F;

    hipMemsetAsync(counts, 0, (size_t)(nbins + B) * sizeof(int), stream);
    bin_kernel<<<dim3((B * F + 63) / 64), dim3(64), 0, stream>>>(
        faces, cA, cB, cC, counts, lists, gcount, glist, B, F);
    raster_kernel<<<dim3(B * 1024), dim3(256), 0, stream>>>(
        textures, cA, cB, cC, counts, lists, gcount, glist, out, B, F);
}